// Round 10
// baseline (138.258 us; speedup 1.0000x reference)
//
#include <hip/hip_runtime.h>
#include <math.h>

// Problem constants
#define BB 16384
#define TT 99
#define RR 10
#define LL 3
#define TILE 33          // 99 = 3*33, processed as 3 chunks of 11 unrolled steps
#define SROW 334         // states LDS stride (floats/row); EVEN -> float2-aligned b64 writes;
                         // 14l mod 32 = 16 bank-pairs x 4 lanes -> conflict-free (verified R9: 551K->95K)
#define PROW 101         // probs LDS stride (floats/row); 101%32=5 -> conflict-free
#define CROW 100         // code byte stride/row; dword stride 25, gcd(25,32)=1 -> conflict-free

// tanh(x) = 1 - 2/(exp(2x)+1); exact limits at +-inf.
__device__ __forceinline__ float fast_tanh(float x) {
    float e = __expf(2.0f * x);
    return fmaf(-2.0f, __builtin_amdgcn_rcpf(e + 1.0f), 1.0f);
}

// One ROW PER LANE. R10: the ONLY change vs R9 is the occupancy attribute.
// R4/R6-R9 all compiled to VGPR=132 with per-step weight refetch because the
// PRE-RA SCHEDULER sinks the ~150 uniform weight loads into the loop to meet
// its default occupancy-driven pressure target; no source phrasing survives
// that. amdgpu_waves_per_eu(1,1) pins max waves/EU = 1 -> pressure budget
// becomes the full 512 VGPRs -> hoisting the loads is legal under the
// scheduler's own cost model.
__global__ __launch_bounds__(64)
__attribute__((amdgpu_waves_per_eu(1, 1)))
void rnn_row_kernel(const int* __restrict__ tok_ids,
                    const float* __restrict__ labels,
                    const float* __restrict__ emb,
                    const float* __restrict__ W,
                    const float* __restrict__ U,
                    const float* __restrict__ bvec,
                    const float* __restrict__ Wo,
                    const float* __restrict__ bo,
                    float* __restrict__ states_out,
                    float* __restrict__ probs_out,
                    float* __restrict__ ws)
{
    __shared__ __align__(16) float         s_st[64 * SROW];   // 85,504 B; preamble: raw labels
    __shared__ __align__(16) float         s_pr[64 * PROW];   // 25,856 B; preamble: raw tokens
    __shared__ __align__(16) unsigned char s_code[64 * CROW]; //  6,400 B  (sel<<2)|y per (row,t)
    __shared__ __align__(16) float         s_w[272];          //  1,088 B  weight staging

    const int l    = threadIdx.x;
    const int row0 = blockIdx.x * 64;

    // ---- preamble A: raw tokens -> s_pr (int4, software-pipelined groups) ----
    {
        const int4* tok4 = reinterpret_cast<const int4*>(tok_ids + (size_t)row0 * TT);
        int4* dst = reinterpret_cast<int4*>(s_pr);
        int4 buf[16];
#pragma unroll 1
        for (int g = 0; g < 2; ++g) {            // 2*16*64 = 2048 >= 1584 pieces
#pragma unroll
            for (int u = 0; u < 16; ++u) {
                const int q = l + 64 * (g * 16 + u);
                if (q < (TT * 64 / 4)) buf[u] = tok4[q];
            }
#pragma unroll
            for (int u = 0; u < 16; ++u) {
                const int q = l + 64 * (g * 16 + u);
                if (q < (TT * 64 / 4)) dst[q] = buf[u];
            }
        }
    }
    // ---- preamble B: raw labels -> s_st (float4 groups) ----
    {
        const float4* lab4 = reinterpret_cast<const float4*>(labels + (size_t)row0 * TT * LL);
        float4* dst = reinterpret_cast<float4*>(s_st);
        float4 buf[16];
#pragma unroll 1
        for (int g = 0; g < 5; ++g) {            // 5*16*64 = 5120 >= 4752 pieces
#pragma unroll
            for (int u = 0; u < 16; ++u) {
                const int q = l + 64 * (g * 16 + u);
                if (q < (TT * LL * 64 / 4)) buf[u] = lab4[q];
            }
#pragma unroll
            for (int u = 0; u < 16; ++u) {
                const int q = l + 64 * (g * 16 + u);
                if (q < (TT * LL * 64 / 4)) dst[q] = buf[u];
            }
        }
    }
    // ---- preamble C: weights -> LDS (strided so ALL 100 elems land) ----
#pragma unroll
    for (int q = 0; q < 2; ++q) {                 // covers 0..127 >= 100
        const int idx = l + 64 * q;
        if (idx < 100) { s_w[idx] = U[idx]; s_w[100 + idx] = W[idx]; }
    }
    if (l < 10)  { s_w[200 + l] = emb[10 + l];    // emb row 1
                   s_w[210 + l] = emb[20 + l];    // emb row 2
                   s_w[220 + l] = bvec[l]; }
    if (l < 30)  { s_w[230 + l] = Wo[l]; }
    if (l < 3)   { s_w[260 + l] = bo[l]; }

    // ---- preamble D: classify own row -> packed code bytes ----
    {
        const int* s_tok_i = reinterpret_cast<const int*>(s_pr);
#pragma unroll 4
        for (int t = 0; t < TT; ++t) {
            const int   tk  = s_tok_i[l * TT + t];
            const float la1 = s_st[(l * TT + t) * LL + 1];
            const float la2 = s_st[(l * TT + t) * LL + 2];
            const int   y   = (la1 > 0.5f) ? 1 : ((la2 > 0.5f) ? 2 : 0);
            s_code[l * CROW + t] = (unsigned char)((tk << 2) | y);
        }
    }

    // ---- weights: LDS -> VGPR arrays (hoist now legal under 512-reg budget) ----
    float Uv[RR][RR];
#pragma unroll
    for (int i = 0; i < RR; ++i)
#pragma unroll
        for (int j = 0; j < RR; ++j)
            Uv[i][j] = s_w[i * RR + j];

    float c1[RR], c2[RR];
#pragma unroll
    for (int j = 0; j < RR; ++j) { c1[j] = s_w[220 + j]; c2[j] = s_w[220 + j]; }
#pragma unroll
    for (int i = 0; i < RR; ++i) {
        const float e1 = s_w[200 + i];
        const float e2 = s_w[210 + i];
#pragma unroll
        for (int j = 0; j < RR; ++j) {
            const float w = s_w[100 + i * RR + j];
            c1[j] = fmaf(e1, w, c1[j]);
            c2[j] = fmaf(e2, w, c2[j]);
        }
    }
    float Woc[RR][LL];
#pragma unroll
    for (int j = 0; j < RR; ++j)
#pragma unroll
        for (int c = 0; c < LL; ++c)
            Woc[j][c] = s_w[230 + j * LL + c];
    const float bo0 = s_w[260], bo1 = s_w[261], bo2 = s_w[262];

    // ---- main sequential loop: 3 tiles x (3 chunks x 11 unrolled steps) ----
    float h[RR];
#pragma unroll
    for (int j = 0; j < RR; ++j) h[j] = 0.0f;
    float loss_acc = 0.0f;
    int   corr = 0;

    int code = (int)s_code[l * CROW];            // prefetch t=0

#pragma unroll 1
    for (int k = 0; k < 3; ++k) {
#pragma unroll 1
        for (int tb = 0; tb < 3; ++tb) {
#pragma unroll
            for (int u = 0; u < 11; ++u) {       // unrolled chunk
                const int tt  = tb * 11 + u;
                const int t   = k * TILE + tt;
                const int cur = code;
                const int tn  = (t + 1 < TT) ? t + 1 : t;
                code = (int)s_code[l * CROW + tn];   // prefetch next step

                const int  sel  = cur >> 2;
                const int  y    = cur & 3;
                const bool is1  = (sel == 1);
                const bool live = (sel != 0);

                float a[RR];
#pragma unroll
                for (int j = 0; j < RR; ++j) a[j] = is1 ? c1[j] : c2[j];
#pragma unroll
                for (int i = 0; i < RR; ++i) {
                    const float hi = h[i];
#pragma unroll
                    for (int j = 0; j < RR; ++j)
                        a[j] = fmaf(hi, Uv[i][j], a[j]);
                }
#pragma unroll
                for (int j = 0; j < RR; ++j) {
                    const float hn = fast_tanh(a[j]);
                    h[j] = live ? hn : h[j];          // Keras masking: carry h
                }

                // stage states: 5x ds_write_b64 (SROW even -> 8B aligned)
                float* sp = &s_st[l * SROW + tt * RR];
#pragma unroll
                for (int j = 0; j < RR; j += 2)
                    *reinterpret_cast<float2*>(sp + j) = make_float2(h[j], h[j + 1]);

                // logits (10x3); softmax WITHOUT max-subtract (|logit| <~ 3)
                float l0 = bo0, l1 = bo1, l2 = bo2;
#pragma unroll
                for (int j = 0; j < RR; ++j) {
                    l0 = fmaf(h[j], Woc[j][0], l0);
                    l1 = fmaf(h[j], Woc[j][1], l1);
                    l2 = fmaf(h[j], Woc[j][2], l2);
                }
                const float e0 = __expf(l0), e1 = __expf(l1), e2 = __expf(l2);
                const float S  = e0 + e1 + e2;
                const float rs = __builtin_amdgcn_rcpf(S);
                float* pp = &s_pr[l * PROW + tt * LL];
                pp[0] = e0 * rs; pp[1] = e1 * rs; pp[2] = e2 * rs;

                // loss: -log(clip(p_y)) == min(logS - l_y, -log(1e-7))
                const float ly = (y == 0) ? l0 : ((y == 1) ? l1 : l2);
                loss_acc += fminf(__logf(S) - ly, 16.11809565f);

                // accuracy: argmax(probs) == argmax(logits)
                int ap = 0; float pm = l0;
                if (l1 > pm) { ap = 1; pm = l1; }
                if (l2 > pm) { ap = 2; }
                corr += (ap == y) ? 1 : 0;
            }
        }

        // ---- flush states tile: LDS -> global, coalesced float2 ----
        {
            const size_t sb = (size_t)row0 * (TT * RR) + (size_t)k * TILE * RR;
#pragma unroll 4
            for (int i = 0; i < 165; ++i) {
                const int q  = l + 64 * i;
                const int r  = q / 165;
                const int m2 = q - r * 165;
                const float v0 = s_st[r * SROW + 2 * m2];
                const float v1 = s_st[r * SROW + 2 * m2 + 1];
                *reinterpret_cast<float2*>(
                    &states_out[sb + (size_t)r * (TT * RR) + 2 * m2]) = make_float2(v0, v1);
            }
        }
        // ---- flush probs tile: coalesced dwords ----
        {
            const size_t pb = (size_t)row0 * (TT * LL) + (size_t)k * TILE * LL;
#pragma unroll 4
            for (int i = 0; i < 99; ++i) {
                const int q  = l + 64 * i;
                const int r  = q / 99;
                const int m1 = q - r * 99;
                probs_out[pb + (size_t)r * (TT * LL) + m1] = s_pr[r * PROW + m1];
            }
        }
        // next tile reuses s_st/s_pr: same-wave DS ordering guarantees safety
    }

    // ---- wave reduction -> one partial per block (deterministic) ----
    float ls = loss_acc;
    float cs = (float)corr;
#pragma unroll
    for (int off = 32; off > 0; off >>= 1) {
        ls += __shfl_down(ls, off, 64);
        cs += __shfl_down(cs, off, 64);
    }
    if (l == 0) {
        ws[blockIdx.x]       = ls;
        ws[256 + blockIdx.x] = cs;
    }
}

__global__ __launch_bounds__(256)
void finalize_kernel(const float* __restrict__ ws, float* __restrict__ out_tail)
{
    __shared__ float sl[4], sc[4];
    const int t = threadIdx.x;
    float ls = ws[t];
    float cs = ws[256 + t];
#pragma unroll
    for (int off = 32; off > 0; off >>= 1) {
        ls += __shfl_down(ls, off, 64);
        cs += __shfl_down(cs, off, 64);
    }
    if ((t & 63) == 0) { sl[t >> 6] = ls; sc[t >> 6] = cs; }
    __syncthreads();
    if (t == 0) {
        const float L = sl[0] + sl[1] + sl[2] + sl[3];
        const float C = sc[0] + sc[1] + sc[2] + sc[3];
        const float inv = 1.0f / (float)((size_t)BB * TT);
        out_tail[0] = C * inv;   // accuracy
        out_tail[1] = L * inv;   // loss
    }
}

extern "C" void kernel_launch(void* const* d_in, const int* in_sizes, int n_in,
                              void* d_out, int out_size, void* d_ws, size_t ws_size,
                              hipStream_t stream)
{
    const int*   tok    = (const int*)  d_in[0];
    const float* labels = (const float*)d_in[1];
    // d_in[2] = mask (unused by reference math)
    const float* emb = (const float*)d_in[3];
    const float* W   = (const float*)d_in[4];
    const float* U   = (const float*)d_in[5];
    const float* bv  = (const float*)d_in[6];
    const float* Wo  = (const float*)d_in[7];
    const float* bo  = (const float*)d_in[8];

    float* out    = (float*)d_out;
    float* states = out;                                  // [B,T,10]
    float* probs  = out + (size_t)BB * TT * RR;           // [B,T,3]
    float* tail   = out + (size_t)BB * TT * (RR + LL);    // accuracy, loss
    float* ws     = (float*)d_ws;                         // 512 floats used

    rnn_row_kernel<<<BB / 64, 64, 0, stream>>>(tok, labels, emb, W, U, bv, Wo, bo,
                                               states, probs, ws);
    finalize_kernel<<<1, 256, 0, stream>>>(ws, tail);
}

// Round 11
// 57.788 us; speedup vs baseline: 2.3925x; 2.3925x over previous
//
#include <hip/hip_runtime.h>
#include <math.h>

// Problem constants
#define BB 16384
#define TT 99
#define RR 10
#define LL 3
#define TILE 33          // 99 = 3*33

// tanh(x) = 1 - 2/(exp(2x)+1); exact limits at +-inf.
__device__ __forceinline__ float fast_tanh(float x) {
    float e = __expf(2.0f * x);
    return fmaf(-2.0f, __builtin_amdgcn_rcpf(e + 1.0f), 1.0f);
}

// ============================ K1: recurrence =============================
// 8 lanes per row; lane (r8,g) owns h-unit g (and 8+g for g<2). Full h is
// gathered each step with 10 register shfls (ds_bpermute) -- NO LDS on the
// recurrence chain (R3's store->wait->reload killed it). No epilogue here.
// Per-lane live set ~60 VGPR (lane-varying -> allocator must keep in regs),
// which sidesteps the VGPR=132 uniform-weight refetch wall of R4-R10.
// Block = 256 thr = 4 waves; each wave owns 8 rows and its own LDS slice ->
// no __syncthreads anywhere. Grid 512 blocks = 2048 waves = 8 waves/CU.
__global__ __launch_bounds__(256, 2)
void rnn_state_kernel(const int* __restrict__ tok_ids,
                      const float* __restrict__ emb,
                      const float* __restrict__ U,
                      const float* __restrict__ W,
                      const float* __restrict__ bvec,
                      float* __restrict__ states_out)
{
    __shared__ __align__(16) float         s_st[4][8 * TILE * RR]; // 42,240 B
    __shared__                unsigned char s_tk[4][8 * 100];      //  3,200 B

    const int tid = threadIdx.x;
    const int w   = tid >> 6;
    const int l   = tid & 63;
    const int r8  = l >> 3;                   // row within wave (0..7)
    const int g   = l & 7;                    // unit slot (0..7)
    const int rb  = l & 56;                   // base lane of this row-group
    const int rowbase = blockIdx.x * 32 + w * 8;

    // ---- stage tokens for the wave's 8 rows (coalesced: gidx = rowbase*99+q) ----
#pragma unroll
    for (int i = 0; i < 13; ++i) {
        const int q = l + 64 * i;
        if (q < 8 * TT) {
            const int tk = tok_ids[(size_t)rowbase * TT + q];
            const int r  = q / TT;
            s_tk[w][q + r] = (unsigned char)tk;   // addr = r*100 + (q - r*99) = q + r
        }
    }

    // ---- per-lane weight columns (lane-varying -> VGPR-resident) ----
    const int jg0 = g;
    const int jg1 = (g < 2) ? 8 + g : g;      // duplicate for g>=2 (unused result)
    float U0[RR], U1[RR];
    float c10 = bvec[jg0], c20 = c10;
    float c11 = bvec[jg1], c21 = c11;
#pragma unroll
    for (int i = 0; i < RR; ++i) {
        U0[i] = U[i * RR + jg0];
        U1[i] = U[i * RR + jg1];
        const float w0 = W[i * RR + jg0];
        const float w1 = W[i * RR + jg1];
        c10 = fmaf(emb[RR + i],     w0, c10);   // token-1 row of emb
        c20 = fmaf(emb[2 * RR + i], w0, c20);   // token-2 row
        c11 = fmaf(emb[RR + i],     w1, c11);
        c21 = fmaf(emb[2 * RR + i], w1, c21);
    }

    float ho0 = 0.0f, ho1 = 0.0f;             // this lane's owned h units
    int sel = (int)s_tk[w][r8 * 100 + 0];     // prefetch t=0

#pragma unroll 1
    for (int k = 0; k < 3; ++k) {
#pragma unroll 1
        for (int tt = 0; tt < TILE; ++tt) {
            const int t   = k * TILE + tt;
            const int cur = sel;
            const int tn  = (t + 1 < TT) ? t + 1 : t;
            sel = (int)s_tk[w][r8 * 100 + tn];        // prefetch next (off-chain)

            // gather full h from the 8-lane group (register shfls, pipelined)
            float h[RR];
#pragma unroll
            for (int i = 0; i < 8; ++i) h[i] = __shfl(ho0, rb + i, 64);
            h[8] = __shfl(ho1, rb + 0, 64);
            h[9] = __shfl(ho1, rb + 1, 64);

            float a0 = (cur == 1) ? c10 : c20;
            float a1 = (cur == 1) ? c11 : c21;
#pragma unroll
            for (int i = 0; i < RR; ++i) {
                a0 = fmaf(h[i], U0[i], a0);
                a1 = fmaf(h[i], U1[i], a1);
            }
            const float hn0 = fast_tanh(a0);
            const float hn1 = fast_tanh(a1);
            if (cur != 0) { ho0 = hn0; ho1 = hn1; }   // Keras masking: carry h

            // stage own units (fire-and-forget b32; <=3-way banked, 2 instrs)
            float* sp = &s_st[w][r8 * (TILE * RR) + tt * RR];
            sp[g] = ho0;
            if (g < 2) sp[8 + g] = ho1;
        }

        // ---- flush tile: 8 rows x 330 floats = 1320 float2, coalesced ----
        const size_t gb = (size_t)rowbase * (TT * RR) + (size_t)k * (TILE * RR);
#pragma unroll
        for (int i = 0; i < 21; ++i) {
            const int q = l + 64 * i;
            if (q < 1320) {
                const int r = q / 165;
                const int m = q - r * 165;
                const float2 v = *reinterpret_cast<const float2*>(
                    &s_st[w][r * (TILE * RR) + 2 * m]);
                *reinterpret_cast<float2*>(
                    &states_out[gb + (size_t)r * (TT * RR) + 2 * m]) = v;
            }
        }
        // next tile reuses s_st: same-wave DS ordering guarantees safety
    }
}

// ============================ K2: epilogue ===============================
// Fully parallel over (b,t): dense+softmax+probs+loss+acc. Memory-bound at
// full occupancy. 2048 blocks x 256; grid-stride; deterministic block partials.
__global__ __launch_bounds__(256)
void epilogue_kernel(const float* __restrict__ states,
                     const float* __restrict__ labels,
                     const float* __restrict__ Wo,
                     const float* __restrict__ bo,
                     float* __restrict__ probs_out,
                     float* __restrict__ ws)
{
    const int NT     = BB * TT;               // 1,622,016
    const int tid    = blockIdx.x * 256 + threadIdx.x;
    const int stride = 2048 * 256;

    // uniform weights (small live set -> happily SGPR/hoisted)
    float Wc0[RR], Wc1[RR], Wc2[RR];
#pragma unroll
    for (int j = 0; j < RR; ++j) {
        Wc0[j] = Wo[j * LL + 0];
        Wc1[j] = Wo[j * LL + 1];
        Wc2[j] = Wo[j * LL + 2];
    }
    const float b0 = bo[0], b1 = bo[1], b2 = bo[2];

    float loss = 0.0f;
    int   corr = 0;

#pragma unroll 1
    for (int idx = tid; idx < NT; idx += stride) {
        const float* hp = states + (size_t)idx * RR;   // 8B-aligned (40B stride)
        float h[RR];
#pragma unroll
        for (int j = 0; j < RR; j += 2) {
            const float2 v = *reinterpret_cast<const float2*>(hp + j);
            h[j] = v.x; h[j + 1] = v.y;
        }
        const float la1 = labels[(size_t)idx * LL + 1];
        const float la2 = labels[(size_t)idx * LL + 2];
        const int   y   = (la1 > 0.5f) ? 1 : ((la2 > 0.5f) ? 2 : 0);

        float l0 = b0, l1 = b1, l2 = b2;
#pragma unroll
        for (int j = 0; j < RR; ++j) {
            l0 = fmaf(h[j], Wc0[j], l0);
            l1 = fmaf(h[j], Wc1[j], l1);
            l2 = fmaf(h[j], Wc2[j], l2);
        }
        const float e0 = __expf(l0), e1 = __expf(l1), e2 = __expf(l2);
        const float S  = e0 + e1 + e2;
        const float rs = __builtin_amdgcn_rcpf(S);
        probs_out[(size_t)idx * LL + 0] = e0 * rs;
        probs_out[(size_t)idx * LL + 1] = e1 * rs;
        probs_out[(size_t)idx * LL + 2] = e2 * rs;

        // loss: -log(clip(p_y, 1e-7, 1)) == min(logS - l_y, -log(1e-7))
        const float ly = (y == 0) ? l0 : ((y == 1) ? l1 : l2);
        loss += fminf(__logf(S) - ly, 16.11809565f);

        // accuracy: argmax(logits) == argmax(probs) (monotonic, same ties)
        int ap = 0; float pm = l0;
        if (l1 > pm) { ap = 1; pm = l1; }
        if (l2 > pm) { ap = 2; }
        corr += (ap == y) ? 1 : 0;
    }

    // block reduction -> one partial pair per block (deterministic)
    __shared__ float sl[4], sc[4];
    float ls = loss, cs = (float)corr;
#pragma unroll
    for (int off = 32; off > 0; off >>= 1) {
        ls += __shfl_down(ls, off, 64);
        cs += __shfl_down(cs, off, 64);
    }
    if ((threadIdx.x & 63) == 0) { sl[threadIdx.x >> 6] = ls; sc[threadIdx.x >> 6] = cs; }
    __syncthreads();
    if (threadIdx.x == 0) {
        ws[blockIdx.x]        = sl[0] + sl[1] + sl[2] + sl[3];
        ws[2048 + blockIdx.x] = sc[0] + sc[1] + sc[2] + sc[3];
    }
}

__global__ __launch_bounds__(256)
void finalize_kernel(const float* __restrict__ ws, float* __restrict__ out_tail)
{
    __shared__ float sl[4], sc[4];
    const int t = threadIdx.x;
    float ls = 0.0f, cs = 0.0f;
#pragma unroll
    for (int i = 0; i < 8; ++i) {
        ls += ws[t + 256 * i];
        cs += ws[2048 + t + 256 * i];
    }
#pragma unroll
    for (int off = 32; off > 0; off >>= 1) {
        ls += __shfl_down(ls, off, 64);
        cs += __shfl_down(cs, off, 64);
    }
    if ((t & 63) == 0) { sl[t >> 6] = ls; sc[t >> 6] = cs; }
    __syncthreads();
    if (t == 0) {
        const float L = sl[0] + sl[1] + sl[2] + sl[3];
        const float C = sc[0] + sc[1] + sc[2] + sc[3];
        const float inv = 1.0f / (float)((size_t)BB * TT);
        out_tail[0] = C * inv;   // accuracy
        out_tail[1] = L * inv;   // loss
    }
}

extern "C" void kernel_launch(void* const* d_in, const int* in_sizes, int n_in,
                              void* d_out, int out_size, void* d_ws, size_t ws_size,
                              hipStream_t stream)
{
    const int*   tok    = (const int*)  d_in[0];
    const float* labels = (const float*)d_in[1];
    // d_in[2] = mask (unused by reference math)
    const float* emb = (const float*)d_in[3];
    const float* W   = (const float*)d_in[4];
    const float* U   = (const float*)d_in[5];
    const float* bv  = (const float*)d_in[6];
    const float* Wo  = (const float*)d_in[7];
    const float* bo  = (const float*)d_in[8];

    float* out    = (float*)d_out;
    float* states = out;                                  // [B,T,10]
    float* probs  = out + (size_t)BB * TT * RR;           // [B,T,3]
    float* tail   = out + (size_t)BB * TT * (RR + LL);    // accuracy, loss
    float* ws     = (float*)d_ws;                         // 4096 floats used

    rnn_state_kernel<<<BB / 32, 256, 0, stream>>>(tok, emb, U, W, bv, states);
    epilogue_kernel<<<2048, 256, 0, stream>>>(states, labels, Wo, bo, probs, ws);
    finalize_kernel<<<1, 256, 0, stream>>>(ws, tail);
}

// Round 12
// 50.095 us; speedup vs baseline: 2.7599x; 1.1536x over previous
//
#include <hip/hip_runtime.h>
#include <math.h>

// Problem constants
#define BB 16384
#define TT 99
#define RR 10
#define LL 3
#define TILE 33          // 99 = 3*33

// tanh(x) = 1 - 2/(exp(2x)+1); exact limits at +-inf.
__device__ __forceinline__ float fast_tanh(float x) {
    float e = __expf(2.0f * x);
    return fmaf(-2.0f, __builtin_amdgcn_rcpf(e + 1.0f), 1.0f);
}

// ========================= K1: recurrence + epilogue =========================
// 8 lanes per row; lane (r8,g) owns h-unit g (and 8+g for g<2). Full h is
// gathered each step with 10 register shfls -- no LDS on the recurrence chain.
// NEW vs R11: the dense/softmax/loss/acc epilogue is fused into the per-TILE
// flush phase (wave-parallel over the tile's 264 (b,t) pairs, 5 rounds of 64
// lanes) -- NOT into the sequential step loop (R3's mistake). This removes
// R11's K2 and its 65 MB states re-read.
// Block = 256 thr = 4 waves; each wave owns 8 rows and its own LDS slice ->
// no __syncthreads anywhere. Grid 512 blocks = 2048 waves = 8 waves/CU.
__global__ __launch_bounds__(256, 2)
void rnn_fused_kernel(const int* __restrict__ tok_ids,
                      const float* __restrict__ labels,
                      const float* __restrict__ emb,
                      const float* __restrict__ W,
                      const float* __restrict__ U,
                      const float* __restrict__ bvec,
                      const float* __restrict__ Wo,
                      const float* __restrict__ bo,
                      float* __restrict__ states_out,
                      float* __restrict__ probs_out,
                      float* __restrict__ ws)
{
    __shared__ __align__(16) float          s_st[4][8 * TILE * RR]; // 42,240 B
    __shared__                unsigned char s_tk[4][8 * 100];       //  3,200 B

    const int tid = threadIdx.x;
    const int w   = tid >> 6;
    const int l   = tid & 63;
    const int r8  = l >> 3;                   // row within wave (0..7)
    const int g   = l & 7;                    // unit slot (0..7)
    const int rb  = l & 56;                   // base lane of this row-group
    const int rowbase = blockIdx.x * 32 + w * 8;

    // ---- stage tokens for the wave's 8 rows (coalesced) ----
#pragma unroll
    for (int i = 0; i < 13; ++i) {
        const int q = l + 64 * i;
        if (q < 8 * TT) {
            const int tk = tok_ids[(size_t)rowbase * TT + q];
            const int r  = q / TT;
            s_tk[w][q + r] = (unsigned char)tk;   // addr = r*100 + (q - r*99)
        }
    }

    // ---- per-lane weight columns (lane-varying -> VGPR-resident) ----
    const int jg0 = g;
    const int jg1 = (g < 2) ? 8 + g : g;      // duplicate for g>=2 (unused result)
    float U0[RR], U1[RR];
    float c10 = bvec[jg0], c20 = c10;
    float c11 = bvec[jg1], c21 = c11;
#pragma unroll
    for (int i = 0; i < RR; ++i) {
        U0[i] = U[i * RR + jg0];
        U1[i] = U[i * RR + jg1];
        const float w0 = W[i * RR + jg0];
        const float w1 = W[i * RR + jg1];
        c10 = fmaf(emb[RR + i],     w0, c10);   // token-1 row of emb
        c20 = fmaf(emb[2 * RR + i], w0, c20);   // token-2 row
        c11 = fmaf(emb[RR + i],     w1, c11);
        c21 = fmaf(emb[2 * RR + i], w1, c21);
    }

    float ho0 = 0.0f, ho1 = 0.0f;             // this lane's owned h units
    float loss = 0.0f;
    int   corr = 0;
    int sel = (int)s_tk[w][r8 * 100 + 0];     // prefetch t=0

#pragma unroll 1
    for (int k = 0; k < 3; ++k) {
        // ================== sequential phase: 33 steps ==================
#pragma unroll 1
        for (int tt = 0; tt < TILE; ++tt) {
            const int t   = k * TILE + tt;
            const int cur = sel;
            const int tn  = (t + 1 < TT) ? t + 1 : t;
            sel = (int)s_tk[w][r8 * 100 + tn];        // prefetch next (off-chain)

            // gather full h from the 8-lane group (register shfls)
            float h[RR];
#pragma unroll
            for (int i = 0; i < 8; ++i) h[i] = __shfl(ho0, rb + i, 64);
            h[8] = __shfl(ho1, rb + 0, 64);
            h[9] = __shfl(ho1, rb + 1, 64);

            float a0 = (cur == 1) ? c10 : c20;
            float a1 = (cur == 1) ? c11 : c21;
#pragma unroll
            for (int i = 0; i < RR; ++i) {
                a0 = fmaf(h[i], U0[i], a0);
                a1 = fmaf(h[i], U1[i], a1);
            }
            const float hn0 = fast_tanh(a0);
            const float hn1 = fast_tanh(a1);
            if (cur != 0) { ho0 = hn0; ho1 = hn1; }   // Keras masking: carry h

            // stage own units (fire-and-forget b32)
            float* sp = &s_st[w][r8 * (TILE * RR) + tt * RR];
            sp[g] = ho0;
            if (g < 2) sp[8 + g] = ho1;
        }

        // ================== parallel phase (per tile) ==================
        const int    t0 = k * TILE;
        const size_t gb = (size_t)rowbase * (TT * RR) + (size_t)k * (TILE * RR);

        // ---- flush states: 8 rows x 330 floats = 1320 float2, coalesced ----
#pragma unroll
        for (int i = 0; i < 21; ++i) {
            const int q = l + 64 * i;
            if (q < 1320) {
                const int r = q / 165;
                const int m = q - r * 165;
                const float2 v = *reinterpret_cast<const float2*>(
                    &s_st[w][r * (TILE * RR) + 2 * m]);
                *reinterpret_cast<float2*>(
                    &states_out[gb + (size_t)r * (TT * RR) + 2 * m]) = v;
            }
        }

        // ---- fused epilogue: 264 (row,step) pairs, wave-parallel ----
#pragma unroll
        for (int i = 0; i < 5; ++i) {
            const int p = l + 64 * i;
            if (p < 8 * TILE) {
                const int r  = p / TILE;
                const int tt = p - r * TILE;
                const size_t idx = (size_t)(rowbase + r) * TT + t0 + tt;

                // h from LDS (row stride 330: lanes stride 10 -> <=4-way banked)
                const float* hp = &s_st[w][r * (TILE * RR) + tt * RR];
                float l0 = bo[0], l1 = bo[1], l2 = bo[2];
#pragma unroll
                for (int j = 0; j < RR; ++j) {
                    const float hj = hp[j];
                    l0 = fmaf(hj, Wo[j * LL + 0], l0);
                    l1 = fmaf(hj, Wo[j * LL + 1], l1);
                    l2 = fmaf(hj, Wo[j * LL + 2], l2);
                }
                const float e0 = __expf(l0), e1 = __expf(l1), e2 = __expf(l2);
                const float S  = e0 + e1 + e2;
                const float rs = __builtin_amdgcn_rcpf(S);
                probs_out[idx * LL + 0] = e0 * rs;
                probs_out[idx * LL + 1] = e1 * rs;
                probs_out[idx * LL + 2] = e2 * rs;

                const float la1 = labels[idx * LL + 1];
                const float la2 = labels[idx * LL + 2];
                const int   y   = (la1 > 0.5f) ? 1 : ((la2 > 0.5f) ? 2 : 0);

                // loss: -log(clip(p_y, 1e-7, 1)) == min(logS - l_y, -log(1e-7))
                const float ly = (y == 0) ? l0 : ((y == 1) ? l1 : l2);
                loss += fminf(__logf(S) - ly, 16.11809565f);

                // accuracy: argmax(logits) == argmax(probs)
                int ap = 0; float pm = l0;
                if (l1 > pm) { ap = 1; pm = l1; }
                if (l2 > pm) { ap = 2; }
                corr += (ap == y) ? 1 : 0;
            }
        }
        // next tile reuses s_st: same-wave DS ordering guarantees safety
    }

    // ---- wave reduction -> one partial per wave (deterministic) ----
    float ls = loss, cs = (float)corr;
#pragma unroll
    for (int off = 32; off > 0; off >>= 1) {
        ls += __shfl_down(ls, off, 64);
        cs += __shfl_down(cs, off, 64);
    }
    if (l == 0) {
        const int wid = blockIdx.x * 4 + w;   // 0..2047
        ws[wid]        = ls;
        ws[2048 + wid] = cs;
    }
}

__global__ __launch_bounds__(256)
void finalize_kernel(const float* __restrict__ ws, float* __restrict__ out_tail)
{
    __shared__ float sl[4], sc[4];
    const int t = threadIdx.x;
    float ls = 0.0f, cs = 0.0f;
#pragma unroll
    for (int i = 0; i < 8; ++i) {
        ls += ws[t + 256 * i];
        cs += ws[2048 + t + 256 * i];
    }
#pragma unroll
    for (int off = 32; off > 0; off >>= 1) {
        ls += __shfl_down(ls, off, 64);
        cs += __shfl_down(cs, off, 64);
    }
    if ((t & 63) == 0) { sl[t >> 6] = ls; sc[t >> 6] = cs; }
    __syncthreads();
    if (t == 0) {
        const float L = sl[0] + sl[1] + sl[2] + sl[3];
        const float C = sc[0] + sc[1] + sc[2] + sc[3];
        const float inv = 1.0f / (float)((size_t)BB * TT);
        out_tail[0] = C * inv;   // accuracy
        out_tail[1] = L * inv;   // loss
    }
}

extern "C" void kernel_launch(void* const* d_in, const int* in_sizes, int n_in,
                              void* d_out, int out_size, void* d_ws, size_t ws_size,
                              hipStream_t stream)
{
    const int*   tok    = (const int*)  d_in[0];
    const float* labels = (const float*)d_in[1];
    // d_in[2] = mask (unused by reference math)
    const float* emb = (const float*)d_in[3];
    const float* W   = (const float*)d_in[4];
    const float* U   = (const float*)d_in[5];
    const float* bv  = (const float*)d_in[6];
    const float* Wo  = (const float*)d_in[7];
    const float* bo  = (const float*)d_in[8];

    float* out    = (float*)d_out;
    float* states = out;                                  // [B,T,10]
    float* probs  = out + (size_t)BB * TT * RR;           // [B,T,3]
    float* tail   = out + (size_t)BB * TT * (RR + LL);    // accuracy, loss
    float* ws     = (float*)d_ws;                         // 4096 floats used

    rnn_fused_kernel<<<BB / 32, 256, 0, stream>>>(tok, labels, emb, W, U, bv, Wo, bo,
                                                  states, probs, ws);
    finalize_kernel<<<1, 256, 0, stream>>>(ws, tail);
}